// Round 14
// baseline (180.408 us; speedup 1.0000x reference)
//
#include <hip/hip_runtime.h>
#include <math.h>

// ALiBi attention: B=2, T=2048, D=1024, H=16, hd=64. fp32 in/out.
// Round 21: split-K gemm_qkv. Accounting shows qkv (~50us, 3 blocks/CU
// lockstep) is the largest kernel. K=1024 -> 2x512 halves, grid (32,8,6)
// = 1536 blocks = 6/CU; identical tile geometry/per-iter structure (r16
// lesson: don't shrink tiles for TLP). bf16 partials (2 planes/matrix) +
// tiny addk kernel folds halves into Qb/Kb/Vb. One extra bf16 rounding on
// Q/K/V (partials are half-magnitude sums; 3x absmax headroom).
// Flash (r18), gemm_out (r20), convert, combine byte-identical.

#define T_SEQ 2048
#define DM    1024
#define NH    16
#define HD    64
#define NROW  4096   // B*T
#define NCHB  80     // chunks per (h,b): qt/8 -> 1,2,3,4 chunks

typedef __attribute__((ext_vector_type(8))) short bf16x8;
typedef __attribute__((ext_vector_type(4))) short bf16x4;
typedef __attribute__((ext_vector_type(4))) float f32x4;

template <bool M> struct BoolT { static constexpr bool value = M; };

__device__ __forceinline__ short f2bf(float f) {
  unsigned u = __float_as_uint(f);
  u += 0x7FFFu + ((u >> 16) & 1u);
  return (short)(u >> 16);
}
__device__ __forceinline__ float bf2f(short s) {
  return __uint_as_float(((unsigned)(unsigned short)s) << 16);
}

// RNE pack of two f32 -> {lo16=bf16(a), hi16=bf16(b)} in one instruction.
__device__ __forceinline__ unsigned cvt_pk_bf16(float a, float b) {
  unsigned r;
  asm("v_cvt_pk_bf16_f32 %0, %1, %2" : "=v"(r) : "v"(a), "v"(b));
  return r;
}

// v_permlane32_swap_b32 a, b: a.hi32lanes <-> b.lo32lanes.
__device__ __forceinline__ void permlane32_swap(unsigned &a, unsigned &b) {
  asm("v_permlane32_swap_b32 %0, %1" : "+v"(a), "+v"(b));
}

#if __has_builtin(__builtin_amdgcn_exp2f)
#define EXP2F(x) __builtin_amdgcn_exp2f(x)
#else
#define EXP2F(x) exp2f(x)
#endif

// ---------------------------------------------------------------------------
// Merged fp32->bf16 conversion: x (4M) + 4 weights (1M each), 2M float4 groups.
// ---------------------------------------------------------------------------
__global__ __launch_bounds__(256) void convert_all(
    const float* __restrict__ x,  const float* __restrict__ wq,
    const float* __restrict__ wk, const float* __restrict__ wv,
    const float* __restrict__ wo,
    short* __restrict__ xb,  short* __restrict__ wqb, short* __restrict__ wkb,
    short* __restrict__ wvb, short* __restrict__ wob) {
  const int i = blockIdx.x * 256 + threadIdx.x;
  const float* s; short* d; int off;
  if (i < (1 << 20)) { s = x; d = xb; off = i; }
  else {
    const int j = i - (1 << 20);
    const int w = j >> 18;
    off = j & ((1 << 18) - 1);
    s = (w == 0) ? wq : (w == 1) ? wk : (w == 2) ? wv : wo;
    d = (w == 0) ? wqb : (w == 1) ? wkb : (w == 2) ? wvb : wob;
  }
  const float4 v = ((const float4*)s)[off];
  bf16x4 o = {f2bf(v.x), f2bf(v.y), f2bf(v.z), f2bf(v.w)};
  *(bf16x4*)(d + 4 * (size_t)off) = o;
}

// ---------------------------------------------------------------------------
// GEMM 128x128, BK=64, early-issue reg staging (r20 verified), K-range
// [kbeg, kbeg+klen): C[m][n] = sum_k A[m][k]*W[n][k] over the range.
// ---------------------------------------------------------------------------
template <typename OutT>
__device__ __forceinline__ void gemm_bk64_body(const short* __restrict__ A,
                                               const short* __restrict__ W,
                                               OutT* __restrict__ C,
                                               int kbeg, int klen) {
  __shared__ short sA0[128][32];
  __shared__ short sA1[128][32];
  __shared__ short sB0[128][32];
  __shared__ short sB1[128][32];
  const int tid  = threadIdx.x;
  const int lane = tid & 63, wv = tid >> 6;
  const int quad = lane >> 4, l16 = lane & 15;
  const int wm = (wv >> 1) * 64, wn = (wv & 1) * 64;
  const size_t m0 = (size_t)blockIdx.x * 128, n0 = (size_t)blockIdx.y * 128;

  f32x4 acc[4][4];
#pragma unroll
  for (int i = 0; i < 4; ++i)
#pragma unroll
    for (int j = 0; j < 4; ++j) acc[i][j] = (f32x4){0.f, 0.f, 0.f, 0.f};

  const int grow = lane >> 2;          // 0..15
  const int gcol = (lane & 3) << 3;    // 0..24 shorts (within 32-col half)

  bf16x8 ra[4], rb[4];                 // staged tile regs (one iter early)
  auto loadT = [&](int k0) {
    const short* ga = A + (m0 + wv * 32 + grow) * DM + k0 + gcol;
    ra[0] = *(const bf16x8*)ga;
    ra[1] = *(const bf16x8*)(ga + 16 * DM);
    ra[2] = *(const bf16x8*)(ga + 32);
    ra[3] = *(const bf16x8*)(ga + 16 * DM + 32);
    const short* gb = W + (n0 + wv * 32 + grow) * DM + k0 + gcol;
    rb[0] = *(const bf16x8*)gb;
    rb[1] = *(const bf16x8*)(gb + 16 * DM);
    rb[2] = *(const bf16x8*)(gb + 32);
    rb[3] = *(const bf16x8*)(gb + 16 * DM + 32);
  };
  auto writeT = [&]() {
    *(bf16x8*)&sA0[wv * 32 + grow][gcol]      = ra[0];
    *(bf16x8*)&sA0[wv * 32 + 16 + grow][gcol] = ra[1];
    *(bf16x8*)&sA1[wv * 32 + grow][gcol]      = ra[2];
    *(bf16x8*)&sA1[wv * 32 + 16 + grow][gcol] = ra[3];
    *(bf16x8*)&sB0[wv * 32 + grow][gcol]      = rb[0];
    *(bf16x8*)&sB0[wv * 32 + 16 + grow][gcol] = rb[1];
    *(bf16x8*)&sB1[wv * 32 + grow][gcol]      = rb[2];
    *(bf16x8*)&sB1[wv * 32 + 16 + grow][gcol] = rb[3];
  };

  loadT(kbeg);   // prologue: issue first tile's loads (regs only)

  const int kend = kbeg + klen;
  for (int k0 = kbeg; k0 < kend; k0 += 64) {
    __syncthreads();                 // LDS free (prev iter's readers done)
    writeT();                        // vmcnt wait here: loads one iter old
    if (k0 + 64 < kend) loadT(k0 + 64);
    __syncthreads();                 // staged LDS visible

    {
      bf16x8 af[4], bfr[4];
#pragma unroll
      for (int t = 0; t < 4; ++t) {
        af[t]  = *(const bf16x8*)&sA0[wm + t * 16 + l16][quad * 8];
        bfr[t] = *(const bf16x8*)&sB0[wn + t * 16 + l16][quad * 8];
      }
#pragma unroll
      for (int mt = 0; mt < 4; ++mt)
#pragma unroll
        for (int nt = 0; nt < 4; ++nt)
          acc[mt][nt] = __builtin_amdgcn_mfma_f32_16x16x32_bf16(af[mt], bfr[nt], acc[mt][nt], 0, 0, 0);
    }
    {
      bf16x8 af[4], bfr[4];
#pragma unroll
      for (int t = 0; t < 4; ++t) {
        af[t]  = *(const bf16x8*)&sA1[wm + t * 16 + l16][quad * 8];
        bfr[t] = *(const bf16x8*)&sB1[wn + t * 16 + l16][quad * 8];
      }
#pragma unroll
      for (int mt = 0; mt < 4; ++mt)
#pragma unroll
        for (int nt = 0; nt < 4; ++nt)
          acc[mt][nt] = __builtin_amdgcn_mfma_f32_16x16x32_bf16(af[mt], bfr[nt], acc[mt][nt], 0, 0, 0);
    }
  }
#pragma unroll
  for (int mt = 0; mt < 4; ++mt) {
#pragma unroll
    for (int r = 0; r < 4; ++r) {
      const size_t m = m0 + wm + mt * 16 + quad * 4 + r;
      OutT* crow = C + m * DM;
#pragma unroll
      for (int nt = 0; nt < 4; ++nt) {
        const float v = acc[mt][nt][r];
        if constexpr (sizeof(OutT) == 2)
          crow[n0 + wn + nt * 16 + l16] = f2bf(v);
        else
          crow[n0 + wn + nt * 16 + l16] = v;
      }
    }
  }
}

// Split-K qkv: z in [0,6): matrix z>>1, K-half z&1. Writes bf16 partials.
__global__ __launch_bounds__(256) void gemm_qkv(
    const short* __restrict__ x,
    const short* __restrict__ Wq, const short* __restrict__ Wk, const short* __restrict__ Wv,
    short* __restrict__ Pp) {
  const int z = blockIdx.z;
  const int mat = z >> 1, half = z & 1;
  const short* W = (mat == 0) ? Wq : (mat == 1) ? Wk : Wv;
  short* C = Pp + (size_t)z * NROW * DM;
  gemm_bk64_body<short>(x, W, C, half * 512, 512);
}

// Fold the two K-halves: Qb/Kb/Vb are contiguous planes after Pp layout.
__global__ __launch_bounds__(256) void addk(const short* __restrict__ Pp,
                                            short* __restrict__ O) {
  const size_t plane8 = (size_t)NROW * DM / 8;   // bf16x8 vecs per plane
  const size_t total = 3 * plane8;
  for (size_t v = (size_t)blockIdx.x * 256 + threadIdx.x; v < total;
       v += (size_t)gridDim.x * 256) {
    const size_t mat = v / plane8, off = v - mat * plane8;
    bf16x8 a = ((const bf16x8*)Pp)[mat * 2 * plane8 + off];
    bf16x8 b = ((const bf16x8*)Pp)[(mat * 2 + 1) * plane8 + off];
    bf16x8 o;
#pragma unroll
    for (int e = 0; e < 8; ++e) o[e] = f2bf(bf2f(a[e]) + bf2f(b[e]));
    ((bf16x8*)O)[v] = o;
  }
}

// ---------------------------------------------------------------------------
// Output GEMM: 64x128 tile, early-issue reg staging (r20 verified).
// ---------------------------------------------------------------------------
__global__ __launch_bounds__(256) void gemm_out(const short* __restrict__ A,
                                                const short* __restrict__ W,
                                                float* __restrict__ C) {
  __shared__ short sA[64][32];
  __shared__ short sB[128][32];
  const int tid  = threadIdx.x;
  const int lane = tid & 63, wv = tid >> 6;
  const int quad = lane >> 4, l16 = lane & 15;
  const int wm = (wv >> 1) * 32, wn = (wv & 1) * 64;
  const size_t m0 = (size_t)blockIdx.x * 64, n0 = (size_t)blockIdx.y * 128;

  f32x4 acc[2][4];
#pragma unroll
  for (int i = 0; i < 2; ++i)
#pragma unroll
    for (int j = 0; j < 4; ++j) acc[i][j] = (f32x4){0.f, 0.f, 0.f, 0.f};

  const int grow = lane >> 2;
  const int gcol = (lane & 3) << 3;

  bf16x8 rg[3];
  auto loadT = [&](int k0) {
#pragma unroll
    for (int cc = 0; cc < 3; ++cc) {
      const int i = wv * 3 + cc;   // 0..11, wave-uniform per call
      const short* src = (i < 4)
          ? A + (m0 + i * 16 + grow) * DM + k0 + gcol
          : W + (n0 + (i - 4) * 16 + grow) * DM + k0 + gcol;
      rg[cc] = *(const bf16x8*)src;
    }
  };
  auto writeT = [&]() {
#pragma unroll
    for (int cc = 0; cc < 3; ++cc) {
      const int i = wv * 3 + cc;
      short* dst = (i < 4) ? &sA[i * 16 + grow][gcol]
                           : &sB[(i - 4) * 16 + grow][gcol];
      *(bf16x8*)dst = rg[cc];
    }
  };

  loadT(0);

  for (int k0 = 0; k0 < DM; k0 += 32) {
    __syncthreads();
    writeT();
    if (k0 + 32 < DM) loadT(k0 + 32);
    __syncthreads();

    bf16x8 af[2], bfr[4];
#pragma unroll
    for (int t = 0; t < 2; ++t)
      af[t] = *(const bf16x8*)&sA[wm + t * 16 + l16][quad * 8];
#pragma unroll
    for (int t = 0; t < 4; ++t)
      bfr[t] = *(const bf16x8*)&sB[wn + t * 16 + l16][quad * 8];
#pragma unroll
    for (int mt = 0; mt < 2; ++mt)
#pragma unroll
      for (int nt = 0; nt < 4; ++nt)
        acc[mt][nt] = __builtin_amdgcn_mfma_f32_16x16x32_bf16(af[mt], bfr[nt], acc[mt][nt], 0, 0, 0);
  }
#pragma unroll
  for (int mt = 0; mt < 2; ++mt) {
#pragma unroll
    for (int r = 0; r < 4; ++r) {
      const size_t m = m0 + wm + mt * 16 + quad * 4 + r;
      float* crow = C + m * DM;
#pragma unroll
      for (int nt = 0; nt < 4; ++nt)
        crow[n0 + wn + nt * 16 + l16] = acc[mt][nt][r];
    }
  }
}

// ---------------------------------------------------------------------------
// Flash attention, ALiBi, causal — uniform-chunk mapping, swapped QK^T,
// ALiBi distance skip (round-18 verified, byte-identical).
// ---------------------------------------------------------------------------
__global__ __launch_bounds__(256) void flash_alibi(const short* __restrict__ Q,
                                                   const short* __restrict__ K,
                                                   const short* __restrict__ V,
                                                   short* __restrict__ O,
                                                   short* __restrict__ Po,
                                                   float* __restrict__ Pl) {
  __shared__ short sK[64][72];             // [key][dim], padded
  __shared__ unsigned int sVt2[64][34];    // [dim][keypair-permuted]

  const int tid  = threadIdx.x;
  const int lane = tid & 63, wv = tid >> 6;
  const int quad = lane >> 4, l16 = lane & 15;
  const int item = blockIdx.x;

  int qt, j;
  if (item < 8)       { qt = item;                j = 0; }
  else if (item < 24) { qt = 8 + (item - 8) / 2;  j = (item - 8) % 2; }
  else if (item < 48) { qt = 16 + (item - 24) / 3; j = (item - 24) % 3; }
  else                { qt = 24 + (item - 48) / 4; j = (item - 48) % 4; }

  const int n   = qt + 1;
  const int kts = j * 8;
  const int kte = (kts + 8 < n) ? (kts + 8) : n;

  const int h = blockIdx.y, b = blockIdx.z;
  const size_t base = (size_t)b * T_SEQ * DM + (size_t)h * HD;
  const int qi_base = qt * 64;

  // Q fragments (identical layout serves as B-operand: col=l16, k=quad*8+j)
  bf16x8 qf[2];
  {
    const int qrow = qi_base + wv * 16 + l16;
    const short* qp = Q + base + (size_t)qrow * DM + quad * 8;
    qf[0] = *(const bf16x8*)(qp);
    qf[1] = *(const bf16x8*)(qp + 32);
  }

  const float slope = exp2f(-0.5f * (float)(h + 1));
  const float sl2   = slope * 1.4426950408889634f;     // slope * log2(e)
  const float C1    = 0.18033688011112042f;            // 0.125 * log2(e)
  const float bA1 = 16.f * sl2, bA2 = 32.f * sl2, bA3 = 48.f * sl2;
  const float c64 = 64.f * sl2;

  // ALiBi skip: keep tile iff qt-kt <= D, D = floor((40/sl2 + 63)/64).
  const int D = (int)((40.0f / sl2 + 63.0f) * 0.015625f);
  const int kmin = qt - D;
  const int kts2 = (kts > kmin) ? kts : kmin;

  const int srow = tid >> 3;          // K staging row (0..31)
  const int scol = (tid & 7) << 3;    // K staging col
  const int kp   = tid >> 3;          // V staging key pair (0..31)
  const int d0   = (tid & 7) << 3;    // V staging dim group
  // PV key-order permutation: physical pair p stored at column col(p).
  const int vcol = ((kp & 3) << 1) + ((kp >> 2) & 1) + (kp & ~7);

  f32x4 oacc[4];
#pragma unroll
  for (int c = 0; c < 4; ++c) oacc[c] = (f32x4){0.f, 0.f, 0.f, 0.f};
  float lsum = 0.f;                   // partial row-sum for query l16

  const int qi = qi_base + wv * 16 + l16;   // this lane's query row
  // bias0[r] = -sl2*(qi - kj) - 12*log2(e) at kj = kts2*64 + quad*4 + r
  float bias0[4];
#pragma unroll
  for (int r = 0; r < 4; ++r)
    bias0[r] = sl2 * (float)(kts2 * 64 + quad * 4 + r - qi) - 17.312340490667562f;

  // staged tile registers: loaded one tile EARLY, written to LDS in the
  // protected staging slot (between the two barriers).
  bf16x8 pka, pkb, pva, pvb;
  auto loadK = [&](int kt) {
    const short* g0 = K + base + (size_t)(kt * 64 + srow) * DM + scol;
    pka = *(const bf16x8*)g0;
    pkb = *(const bf16x8*)(g0 + 32 * DM);
  };
  auto loadV = [&](int kt) {
    const short* v0 = V + base + (size_t)(kt * 64 + 2 * kp) * DM + d0;
    pva = *(const bf16x8*)v0;
    pvb = *(const bf16x8*)(v0 + DM);
  };
  auto writeK = [&]() {
    *(bf16x8*)&sK[srow][scol]      = pka;
    *(bf16x8*)&sK[srow + 32][scol] = pkb;
  };
  auto packV = [&]() {
    const unsigned* au = (const unsigned*)&pva;
    const unsigned* bu = (const unsigned*)&pvb;
#pragma unroll
    for (int e = 0; e < 4; ++e) {
      // {lo16 = pva.short[2e] (key 2kp), hi16 = pvb.short[2e] (key 2kp+1)}
      sVt2[d0 + 2 * e][vcol]     = __builtin_amdgcn_perm(bu[e], au[e], 0x05040100u);
      sVt2[d0 + 2 * e + 1][vcol] = __builtin_amdgcn_perm(bu[e], au[e], 0x07060302u);
    }
  };

  auto tile = [&](int kt, auto mc) {
    constexpr bool MASK = decltype(mc)::value;
    const int k0 = kt * 64;
    __syncthreads();   // protect sK/sVt2 from previous tile's readers
    writeK();          // stage tile t (vmcnt wait: loads are one tile old)
    packV();
    if (kt + 1 < kte) {          // issue next tile's loads (regs)
      loadK(kt + 1);
      loadV(kt + 1);
    }
    __syncthreads();   // staged LDS visible to all waves

    // S^T = K Q^T : lane holds S[key=c*16+quad*4+r][q=l16]
    f32x4 sacc[4];
#pragma unroll
    for (int c = 0; c < 4; ++c) {
      f32x4 a = (f32x4){0.f, 0.f, 0.f, 0.f};
      a = __builtin_amdgcn_mfma_f32_16x16x32_bf16(
              *(const bf16x8*)&sK[c * 16 + l16][quad * 8], qf[0], a, 0, 0, 0);
      a = __builtin_amdgcn_mfma_f32_16x16x32_bf16(
              *(const bf16x8*)&sK[c * 16 + l16][32 + quad * 8], qf[1], a, 0, 0, 0);
      sacc[c] = a;
    }

    // softmax numerator in-lane: p = exp2(sacc*C1 + bias0[r] + bAdd[c])
    const float bAdd[4] = {0.f, bA1, bA2, bA3};
    float pv[4][4];
    int dq = 0;
    if constexpr (MASK) dq = qi - k0 - quad * 4;   // keep if c*16+r <= dq
#pragma unroll
    for (int c = 0; c < 4; ++c) {
#pragma unroll
      for (int r = 0; r < 4; ++r) {
        float p = EXP2F(fmaf(sacc[c][r], C1, bias0[r] + bAdd[c]));
        if constexpr (MASK) p = (c * 16 + r <= dq) ? p : 0.0f;
        pv[c][r] = p;
      }
      lsum += (pv[c][0] + pv[c][1]) + (pv[c][2] + pv[c][3]);
    }

    // O += P V : A-frag assembled in registers (2 swaps per 32-key half)
#pragma unroll
    for (int s = 0; s < 2; ++s) {
      unsigned X = cvt_pk_bf16(pv[2 * s][0],     pv[2 * s][1]);
      unsigned Y = cvt_pk_bf16(pv[2 * s][2],     pv[2 * s][3]);
      unsigned Z = cvt_pk_bf16(pv[2 * s + 1][0], pv[2 * s + 1][1]);
      unsigned W = cvt_pk_bf16(pv[2 * s + 1][2], pv[2 * s + 1][3]);
      permlane32_swap(X, Z);   // X=w0, Z=w1
      permlane32_swap(Y, W);   // Y=w2, W=w3
      bf16x8 pa;
      unsigned* pw = (unsigned*)&pa;
      pw[0] = X; pw[1] = Z; pw[2] = Y; pw[3] = W;
#pragma unroll
      for (int c = 0; c < 4; ++c) {
        const unsigned* vp = &sVt2[c * 16 + l16][s * 16 + quad * 4];
        bf16x4 vlo = *(const bf16x4*)vp;
        bf16x4 vhi = *(const bf16x4*)(vp + 2);
        bf16x8 vf = {vlo[0], vlo[1], vlo[2], vlo[3], vhi[0], vhi[1], vhi[2], vhi[3]};
        oacc[c] = __builtin_amdgcn_mfma_f32_16x16x32_bf16(pa, vf, oacc[c], 0, 0, 0);
      }
    }

#pragma unroll
    for (int r = 0; r < 4; ++r) bias0[r] += c64;   // k0 advances 64 next tile
  };

  if (kts2 < kte) {
    // prologue: issue first tile's loads (regs only; LDS writes in tile 0)
    loadK(kts2);
    loadV(kts2);
    // all tiles except the diagonal (last of the LAST chunk) are fully causal
    const int kfull = (kte == n) ? (kte - 1) : kte;
    for (int kt = kts2; kt < kfull; ++kt) tile(kt, BoolT<false>{});
    if (kte == n) tile(n - 1, BoolT<true>{});   // diagonal tile: mask
  }
  // else: fully-skipped chunk -> zero partials below

  // epilogue: unnormalized O partial (bf16) + l partial (fp32)
  {
    // total l for query l16: reduce over the 4 quad lanes
    float lt = lsum;
    lt += __shfl_xor(lt, 16);
    lt += __shfl_xor(lt, 32);
    const int pidx = (b * NH + h) * NCHB + item;
    short* po = Po + (size_t)pidx * 4096;   // [64 rows][64 dims]
    float* pl = Pl + (size_t)pidx * 64;
#pragma unroll
    for (int r = 0; r < 4; ++r) {
      const int row = wv * 16 + quad * 4 + r;
      const float lr = __shfl(lt, quad * 4 + r, 16);  // l of query quad*4+r
      if (l16 == 0) pl[row] = lr;
#pragma unroll
      for (int c = 0; c < 4; ++c)
        po[row * 64 + c * 16 + l16] = f2bf(oacc[c][r]);
    }
  }
}

// ---------------------------------------------------------------------------
// Combine: O[row] = (sum_j Oj)/(sum_j lj) -> bf16, for ALL query tiles.
// chunks per qt: (qt>>3)+1; slab base cum(qt) = (g+1)*(4g + (qt&7)), g=qt>>3.
// ---------------------------------------------------------------------------
__global__ __launch_bounds__(256) void combine(const short* __restrict__ Po,
                                               const float* __restrict__ Pl,
                                               short* __restrict__ O) {
  const int g = blockIdx.x * 32 + (threadIdx.x >> 3);   // 0..65535
  const int d = (threadIdx.x & 7) << 3;
  const int row = g & 63;
  const int qt  = (g >> 6) & 31;
  const int h   = (g >> 11) & 15;
  const int b   = g >> 15;
  const int gq  = qt >> 3;
  const int nch = gq + 1;
  const int cum = (gq + 1) * (4 * gq + (qt & 7));
  const int sbase = (b * NH + h) * NCHB + cum;

  float l = 0.f;
  float acc[8] = {0.f, 0.f, 0.f, 0.f, 0.f, 0.f, 0.f, 0.f};
  for (int jj = 0; jj < nch; ++jj) {
    l += Pl[(size_t)(sbase + jj) * 64 + row];
    const short* p = Po + (size_t)(sbase + jj) * 4096 + row * 64 + d;
    bf16x8 a = *(const bf16x8*)p;
#pragma unroll
    for (int e = 0; e < 8; ++e) acc[e] += bf2f(a[e]);
  }
  const float inv = 1.0f / fmaxf(l, 1e-37f);
  const int qi = qt * 64 + row;
  short* orow = O + (size_t)b * T_SEQ * DM + (size_t)qi * DM + h * HD + d;
  bf16x8 o;
#pragma unroll
  for (int e = 0; e < 8; ++e) o[e] = f2bf(acc[e] * inv);
  *(bf16x8*)orow = o;
}

// ---------------------------------------------------------------------------
extern "C" void kernel_launch(void* const* d_in, const int* in_sizes, int n_in,
                              void* d_out, int out_size, void* d_ws, size_t ws_size,
                              hipStream_t stream) {
  float* out = (float*)d_out;   // fp32 output

  short* ws = (short*)d_ws;
  const size_t plane = (size_t)NROW * DM;   // 4M elements
  const size_t wsz   = (size_t)DM * DM;     // 1M elements
  const size_t nslab = (size_t)32 * NCHB;   // 2560 partial slabs
  short* xb  = ws;
  short* Wqb = xb + plane;
  short* Wkb = Wqb + wsz;
  short* Wvb = Wkb + wsz;
  short* Wob = Wvb + wsz;
  short* Qb  = Wob + wsz;
  short* Kb  = Qb + plane;
  short* Vb  = Kb + plane;
  short* Ab  = Vb + plane;
  short* Po  = Ab + plane;                  // 2560 slabs * 4096 bf16 = 21 MB
  float* Pl  = (float*)(Po + nslab * 4096); // 2560 * 64 fp32 = 655 KB
  short* Pp  = (short*)(Pl + nslab * 64);   // 6 split-K partial planes, 48 MB

  dim3 blk(256);
  convert_all<<<8192, blk, 0, stream>>>(
      (const float*)d_in[0], (const float*)d_in[1], (const float*)d_in[2],
      (const float*)d_in[3], (const float*)d_in[4],
      xb, Wqb, Wkb, Wvb, Wob);

  gemm_qkv<<<dim3(NROW / 128, DM / 128, 6), blk, 0, stream>>>(xb, Wqb, Wkb, Wvb, Pp);
  addk<<<2048, blk, 0, stream>>>(Pp, Qb);   // Qb,Kb,Vb contiguous
  flash_alibi<<<dim3(NCHB, NH, 2), blk, 0, stream>>>(Qb, Kb, Vb, Ab, Po, Pl);
  combine<<<2048, blk, 0, stream>>>(Po, Pl, Ab);
  gemm_out<<<dim3(NROW / 64, DM / 128, 1), blk, 0, stream>>>(Ab, Wob, out);
}

// Round 15
// 167.051 us; speedup vs baseline: 1.0800x; 1.0800x over previous
//
#include <hip/hip_runtime.h>
#include <math.h>

// ALiBi attention: B=2, T=2048, D=1024, H=16, hd=64. fp32 in/out.
// Round 22: revert round-21 split-K (regressed +14.5us: ~96MB extra partial
// traffic ~= 16us at 6TB/s > any TLP gain). Back to the verified round-20
// state, plus one bit-exact lever: fully-skipped flash chunks (kts2>=kte,
// ~40% of blocks after the ALiBi skip) now return WITHOUT writing zero
// partial slabs, and combine derives the same D(h) (identical fp expression)
// to start its chunk loop at jmin -- skipped slabs contributed exactly 0.
// gemm_qkv/gemm_out (r20 T14 staging), flash core (r18), convert unchanged.

#define T_SEQ 2048
#define DM    1024
#define NH    16
#define HD    64
#define NROW  4096   // B*T
#define NCHB  80     // chunks per (h,b): qt/8 -> 1,2,3,4 chunks

typedef __attribute__((ext_vector_type(8))) short bf16x8;
typedef __attribute__((ext_vector_type(4))) short bf16x4;
typedef __attribute__((ext_vector_type(4))) float f32x4;

template <bool M> struct BoolT { static constexpr bool value = M; };

__device__ __forceinline__ short f2bf(float f) {
  unsigned u = __float_as_uint(f);
  u += 0x7FFFu + ((u >> 16) & 1u);
  return (short)(u >> 16);
}
__device__ __forceinline__ float bf2f(short s) {
  return __uint_as_float(((unsigned)(unsigned short)s) << 16);
}

// RNE pack of two f32 -> {lo16=bf16(a), hi16=bf16(b)} in one instruction.
__device__ __forceinline__ unsigned cvt_pk_bf16(float a, float b) {
  unsigned r;
  asm("v_cvt_pk_bf16_f32 %0, %1, %2" : "=v"(r) : "v"(a), "v"(b));
  return r;
}

// v_permlane32_swap_b32 a, b: a.hi32lanes <-> b.lo32lanes.
__device__ __forceinline__ void permlane32_swap(unsigned &a, unsigned &b) {
  asm("v_permlane32_swap_b32 %0, %1" : "+v"(a), "+v"(b));
}

#if __has_builtin(__builtin_amdgcn_exp2f)
#define EXP2F(x) __builtin_amdgcn_exp2f(x)
#else
#define EXP2F(x) exp2f(x)
#endif

// ALiBi tile-skip horizon, shared by flash_alibi and combine (must be the
// SAME fp expression in both so D(h) matches bit-exactly).
__device__ __forceinline__ int alibi_D(int h) {
  const float sl2 = exp2f(-0.5f * (float)(h + 1)) * 1.4426950408889634f;
  return (int)((40.0f / sl2 + 63.0f) * 0.015625f);
}

// ---------------------------------------------------------------------------
// Merged fp32->bf16 conversion: x (4M) + 4 weights (1M each), 2M float4 groups.
// ---------------------------------------------------------------------------
__global__ __launch_bounds__(256) void convert_all(
    const float* __restrict__ x,  const float* __restrict__ wq,
    const float* __restrict__ wk, const float* __restrict__ wv,
    const float* __restrict__ wo,
    short* __restrict__ xb,  short* __restrict__ wqb, short* __restrict__ wkb,
    short* __restrict__ wvb, short* __restrict__ wob) {
  const int i = blockIdx.x * 256 + threadIdx.x;
  const float* s; short* d; int off;
  if (i < (1 << 20)) { s = x; d = xb; off = i; }
  else {
    const int j = i - (1 << 20);
    const int w = j >> 18;
    off = j & ((1 << 18) - 1);
    s = (w == 0) ? wq : (w == 1) ? wk : (w == 2) ? wv : wo;
    d = (w == 0) ? wqb : (w == 1) ? wkb : (w == 2) ? wvb : wob;
  }
  const float4 v = ((const float4*)s)[off];
  bf16x4 o = {f2bf(v.x), f2bf(v.y), f2bf(v.z), f2bf(v.w)};
  *(bf16x4*)(d + 4 * (size_t)off) = o;
}

// ---------------------------------------------------------------------------
// GEMM 128x128, BK=64, early-issue reg staging (r20 verified):
//   barrier1 -> ds_write regs (loaded one iter ago) -> issue loads(k0+64)
//   -> barrier2 -> 32 MFMAs.
// ---------------------------------------------------------------------------
template <typename OutT>
__device__ __forceinline__ void gemm_bk64_body(const short* __restrict__ A,
                                               const short* __restrict__ W,
                                               OutT* __restrict__ C) {
  __shared__ short sA0[128][32];
  __shared__ short sA1[128][32];
  __shared__ short sB0[128][32];
  __shared__ short sB1[128][32];
  const int tid  = threadIdx.x;
  const int lane = tid & 63, wv = tid >> 6;
  const int quad = lane >> 4, l16 = lane & 15;
  const int wm = (wv >> 1) * 64, wn = (wv & 1) * 64;
  const size_t m0 = (size_t)blockIdx.x * 128, n0 = (size_t)blockIdx.y * 128;

  f32x4 acc[4][4];
#pragma unroll
  for (int i = 0; i < 4; ++i)
#pragma unroll
    for (int j = 0; j < 4; ++j) acc[i][j] = (f32x4){0.f, 0.f, 0.f, 0.f};

  const int grow = lane >> 2;          // 0..15
  const int gcol = (lane & 3) << 3;    // 0..24 shorts (within 32-col half)

  bf16x8 ra[4], rb[4];                 // staged tile regs (one iter early)
  auto loadT = [&](int k0) {
    const short* ga = A + (m0 + wv * 32 + grow) * DM + k0 + gcol;
    ra[0] = *(const bf16x8*)ga;
    ra[1] = *(const bf16x8*)(ga + 16 * DM);
    ra[2] = *(const bf16x8*)(ga + 32);
    ra[3] = *(const bf16x8*)(ga + 16 * DM + 32);
    const short* gb = W + (n0 + wv * 32 + grow) * DM + k0 + gcol;
    rb[0] = *(const bf16x8*)gb;
    rb[1] = *(const bf16x8*)(gb + 16 * DM);
    rb[2] = *(const bf16x8*)(gb + 32);
    rb[3] = *(const bf16x8*)(gb + 16 * DM + 32);
  };
  auto writeT = [&]() {
    *(bf16x8*)&sA0[wv * 32 + grow][gcol]      = ra[0];
    *(bf16x8*)&sA0[wv * 32 + 16 + grow][gcol] = ra[1];
    *(bf16x8*)&sA1[wv * 32 + grow][gcol]      = ra[2];
    *(bf16x8*)&sA1[wv * 32 + 16 + grow][gcol] = ra[3];
    *(bf16x8*)&sB0[wv * 32 + grow][gcol]      = rb[0];
    *(bf16x8*)&sB0[wv * 32 + 16 + grow][gcol] = rb[1];
    *(bf16x8*)&sB1[wv * 32 + grow][gcol]      = rb[2];
    *(bf16x8*)&sB1[wv * 32 + 16 + grow][gcol] = rb[3];
  };

  loadT(0);   // prologue: issue first tile's loads (regs only)

  for (int k0 = 0; k0 < DM; k0 += 64) {
    __syncthreads();                 // LDS free (prev iter's readers done)
    writeT();                        // vmcnt wait here: loads one iter old
    if (k0 + 64 < DM) loadT(k0 + 64);
    __syncthreads();                 // staged LDS visible

    {
      bf16x8 af[4], bfr[4];
#pragma unroll
      for (int t = 0; t < 4; ++t) {
        af[t]  = *(const bf16x8*)&sA0[wm + t * 16 + l16][quad * 8];
        bfr[t] = *(const bf16x8*)&sB0[wn + t * 16 + l16][quad * 8];
      }
#pragma unroll
      for (int mt = 0; mt < 4; ++mt)
#pragma unroll
        for (int nt = 0; nt < 4; ++nt)
          acc[mt][nt] = __builtin_amdgcn_mfma_f32_16x16x32_bf16(af[mt], bfr[nt], acc[mt][nt], 0, 0, 0);
    }
    {
      bf16x8 af[4], bfr[4];
#pragma unroll
      for (int t = 0; t < 4; ++t) {
        af[t]  = *(const bf16x8*)&sA1[wm + t * 16 + l16][quad * 8];
        bfr[t] = *(const bf16x8*)&sB1[wn + t * 16 + l16][quad * 8];
      }
#pragma unroll
      for (int mt = 0; mt < 4; ++mt)
#pragma unroll
        for (int nt = 0; nt < 4; ++nt)
          acc[mt][nt] = __builtin_amdgcn_mfma_f32_16x16x32_bf16(af[mt], bfr[nt], acc[mt][nt], 0, 0, 0);
    }
  }
#pragma unroll
  for (int mt = 0; mt < 4; ++mt) {
#pragma unroll
    for (int r = 0; r < 4; ++r) {
      const size_t m = m0 + wm + mt * 16 + quad * 4 + r;
      OutT* crow = C + m * DM;
#pragma unroll
      for (int nt = 0; nt < 4; ++nt) {
        const float v = acc[mt][nt][r];
        if constexpr (sizeof(OutT) == 2)
          crow[n0 + wn + nt * 16 + l16] = f2bf(v);
        else
          crow[n0 + wn + nt * 16 + l16] = v;
      }
    }
  }
}

__global__ __launch_bounds__(256) void gemm_qkv(
    const short* __restrict__ x,
    const short* __restrict__ Wq, const short* __restrict__ Wk, const short* __restrict__ Wv,
    short* __restrict__ Qb, short* __restrict__ Kb, short* __restrict__ Vb) {
  const short* W = (blockIdx.z == 0) ? Wq : (blockIdx.z == 1) ? Wk : Wv;
  short*       C = (blockIdx.z == 0) ? Qb : (blockIdx.z == 1) ? Kb : Vb;
  gemm_bk64_body<short>(x, W, C);
}

// ---------------------------------------------------------------------------
// Output GEMM: 64x128 tile, early-issue reg staging (r20 verified).
// ---------------------------------------------------------------------------
__global__ __launch_bounds__(256) void gemm_out(const short* __restrict__ A,
                                                const short* __restrict__ W,
                                                float* __restrict__ C) {
  __shared__ short sA[64][32];
  __shared__ short sB[128][32];
  const int tid  = threadIdx.x;
  const int lane = tid & 63, wv = tid >> 6;
  const int quad = lane >> 4, l16 = lane & 15;
  const int wm = (wv >> 1) * 32, wn = (wv & 1) * 64;
  const size_t m0 = (size_t)blockIdx.x * 64, n0 = (size_t)blockIdx.y * 128;

  f32x4 acc[2][4];
#pragma unroll
  for (int i = 0; i < 2; ++i)
#pragma unroll
    for (int j = 0; j < 4; ++j) acc[i][j] = (f32x4){0.f, 0.f, 0.f, 0.f};

  const int grow = lane >> 2;
  const int gcol = (lane & 3) << 3;

  bf16x8 rg[3];
  auto loadT = [&](int k0) {
#pragma unroll
    for (int cc = 0; cc < 3; ++cc) {
      const int i = wv * 3 + cc;   // 0..11, wave-uniform per call
      const short* src = (i < 4)
          ? A + (m0 + i * 16 + grow) * DM + k0 + gcol
          : W + (n0 + (i - 4) * 16 + grow) * DM + k0 + gcol;
      rg[cc] = *(const bf16x8*)src;
    }
  };
  auto writeT = [&]() {
#pragma unroll
    for (int cc = 0; cc < 3; ++cc) {
      const int i = wv * 3 + cc;
      short* dst = (i < 4) ? &sA[i * 16 + grow][gcol]
                           : &sB[(i - 4) * 16 + grow][gcol];
      *(bf16x8*)dst = rg[cc];
    }
  };

  loadT(0);

  for (int k0 = 0; k0 < DM; k0 += 32) {
    __syncthreads();
    writeT();
    if (k0 + 32 < DM) loadT(k0 + 32);
    __syncthreads();

    bf16x8 af[2], bfr[4];
#pragma unroll
    for (int t = 0; t < 2; ++t)
      af[t] = *(const bf16x8*)&sA[wm + t * 16 + l16][quad * 8];
#pragma unroll
    for (int t = 0; t < 4; ++t)
      bfr[t] = *(const bf16x8*)&sB[wn + t * 16 + l16][quad * 8];
#pragma unroll
    for (int mt = 0; mt < 2; ++mt)
#pragma unroll
      for (int nt = 0; nt < 4; ++nt)
        acc[mt][nt] = __builtin_amdgcn_mfma_f32_16x16x32_bf16(af[mt], bfr[nt], acc[mt][nt], 0, 0, 0);
  }
#pragma unroll
  for (int mt = 0; mt < 2; ++mt) {
#pragma unroll
    for (int r = 0; r < 4; ++r) {
      const size_t m = m0 + wm + mt * 16 + quad * 4 + r;
      float* crow = C + m * DM;
#pragma unroll
      for (int nt = 0; nt < 4; ++nt)
        crow[n0 + wn + nt * 16 + l16] = acc[mt][nt][r];
    }
  }
}

// ---------------------------------------------------------------------------
// Flash attention, ALiBi, causal — uniform-chunk mapping, swapped QK^T,
// ALiBi distance skip (r18 verified). Fully-skipped chunks now return
// WITHOUT writing partials (combine skips those slabs via the same D(h)).
// ---------------------------------------------------------------------------
__global__ __launch_bounds__(256) void flash_alibi(const short* __restrict__ Q,
                                                   const short* __restrict__ K,
                                                   const short* __restrict__ V,
                                                   short* __restrict__ O,
                                                   short* __restrict__ Po,
                                                   float* __restrict__ Pl) {
  __shared__ short sK[64][72];             // [key][dim], padded
  __shared__ unsigned int sVt2[64][34];    // [dim][keypair-permuted]

  const int tid  = threadIdx.x;
  const int lane = tid & 63, wv = tid >> 6;
  const int quad = lane >> 4, l16 = lane & 15;
  const int item = blockIdx.x;

  int qt, j;
  if (item < 8)       { qt = item;                j = 0; }
  else if (item < 24) { qt = 8 + (item - 8) / 2;  j = (item - 8) % 2; }
  else if (item < 48) { qt = 16 + (item - 24) / 3; j = (item - 24) % 3; }
  else                { qt = 24 + (item - 48) / 4; j = (item - 48) % 4; }

  const int n   = qt + 1;
  const int kts = j * 8;
  const int kte = (kts + 8 < n) ? (kts + 8) : n;

  const int h = blockIdx.y, b = blockIdx.z;

  // ALiBi skip: keep tile iff qt-kt <= D (shared formula with combine)
  const int D = alibi_D(h);
  const int kmin = qt - D;
  const int kts2 = (kts > kmin) ? kts : kmin;
  if (kts2 >= kte) return;            // fully-skipped chunk: no partials

  const size_t base = (size_t)b * T_SEQ * DM + (size_t)h * HD;
  const int qi_base = qt * 64;

  // Q fragments (identical layout serves as B-operand: col=l16, k=quad*8+j)
  bf16x8 qf[2];
  {
    const int qrow = qi_base + wv * 16 + l16;
    const short* qp = Q + base + (size_t)qrow * DM + quad * 8;
    qf[0] = *(const bf16x8*)(qp);
    qf[1] = *(const bf16x8*)(qp + 32);
  }

  const float slope = exp2f(-0.5f * (float)(h + 1));
  const float sl2   = slope * 1.4426950408889634f;     // slope * log2(e)
  const float C1    = 0.18033688011112042f;            // 0.125 * log2(e)
  const float bA1 = 16.f * sl2, bA2 = 32.f * sl2, bA3 = 48.f * sl2;
  const float c64 = 64.f * sl2;

  const int srow = tid >> 3;          // K staging row (0..31)
  const int scol = (tid & 7) << 3;    // K staging col
  const int kp   = tid >> 3;          // V staging key pair (0..31)
  const int d0   = (tid & 7) << 3;    // V staging dim group
  // PV key-order permutation: physical pair p stored at column col(p).
  const int vcol = ((kp & 3) << 1) + ((kp >> 2) & 1) + (kp & ~7);

  f32x4 oacc[4];
#pragma unroll
  for (int c = 0; c < 4; ++c) oacc[c] = (f32x4){0.f, 0.f, 0.f, 0.f};
  float lsum = 0.f;                   // partial row-sum for query l16

  const int qi = qi_base + wv * 16 + l16;   // this lane's query row
  // bias0[r] = -sl2*(qi - kj) - 12*log2(e) at kj = kts2*64 + quad*4 + r
  float bias0[4];
#pragma unroll
  for (int r = 0; r < 4; ++r)
    bias0[r] = sl2 * (float)(kts2 * 64 + quad * 4 + r - qi) - 17.312340490667562f;

  // staged tile registers: loaded one tile EARLY, written to LDS in the
  // protected staging slot (between the two barriers).
  bf16x8 pka, pkb, pva, pvb;
  auto loadK = [&](int kt) {
    const short* g0 = K + base + (size_t)(kt * 64 + srow) * DM + scol;
    pka = *(const bf16x8*)g0;
    pkb = *(const bf16x8*)(g0 + 32 * DM);
  };
  auto loadV = [&](int kt) {
    const short* v0 = V + base + (size_t)(kt * 64 + 2 * kp) * DM + d0;
    pva = *(const bf16x8*)v0;
    pvb = *(const bf16x8*)(v0 + DM);
  };
  auto writeK = [&]() {
    *(bf16x8*)&sK[srow][scol]      = pka;
    *(bf16x8*)&sK[srow + 32][scol] = pkb;
  };
  auto packV = [&]() {
    const unsigned* au = (const unsigned*)&pva;
    const unsigned* bu = (const unsigned*)&pvb;
#pragma unroll
    for (int e = 0; e < 4; ++e) {
      // {lo16 = pva.short[2e] (key 2kp), hi16 = pvb.short[2e] (key 2kp+1)}
      sVt2[d0 + 2 * e][vcol]     = __builtin_amdgcn_perm(bu[e], au[e], 0x05040100u);
      sVt2[d0 + 2 * e + 1][vcol] = __builtin_amdgcn_perm(bu[e], au[e], 0x07060302u);
    }
  };

  auto tile = [&](int kt, auto mc) {
    constexpr bool MASK = decltype(mc)::value;
    const int k0 = kt * 64;
    __syncthreads();   // protect sK/sVt2 from previous tile's readers
    writeK();          // stage tile t (vmcnt wait: loads are one tile old)
    packV();
    if (kt + 1 < kte) {          // issue next tile's loads (regs)
      loadK(kt + 1);
      loadV(kt + 1);
    }
    __syncthreads();   // staged LDS visible to all waves

    // S^T = K Q^T : lane holds S[key=c*16+quad*4+r][q=l16]
    f32x4 sacc[4];
#pragma unroll
    for (int c = 0; c < 4; ++c) {
      f32x4 a = (f32x4){0.f, 0.f, 0.f, 0.f};
      a = __builtin_amdgcn_mfma_f32_16x16x32_bf16(
              *(const bf16x8*)&sK[c * 16 + l16][quad * 8], qf[0], a, 0, 0, 0);
      a = __builtin_amdgcn_mfma_f32_16x16x32_bf16(
              *(const bf16x8*)&sK[c * 16 + l16][32 + quad * 8], qf[1], a, 0, 0, 0);
      sacc[c] = a;
    }

    // softmax numerator in-lane: p = exp2(sacc*C1 + bias0[r] + bAdd[c])
    const float bAdd[4] = {0.f, bA1, bA2, bA3};
    float pv[4][4];
    int dq = 0;
    if constexpr (MASK) dq = qi - k0 - quad * 4;   // keep if c*16+r <= dq
#pragma unroll
    for (int c = 0; c < 4; ++c) {
#pragma unroll
      for (int r = 0; r < 4; ++r) {
        float p = EXP2F(fmaf(sacc[c][r], C1, bias0[r] + bAdd[c]));
        if constexpr (MASK) p = (c * 16 + r <= dq) ? p : 0.0f;
        pv[c][r] = p;
      }
      lsum += (pv[c][0] + pv[c][1]) + (pv[c][2] + pv[c][3]);
    }

    // O += P V : A-frag assembled in registers (2 swaps per 32-key half)
#pragma unroll
    for (int s = 0; s < 2; ++s) {
      unsigned X = cvt_pk_bf16(pv[2 * s][0],     pv[2 * s][1]);
      unsigned Y = cvt_pk_bf16(pv[2 * s][2],     pv[2 * s][3]);
      unsigned Z = cvt_pk_bf16(pv[2 * s + 1][0], pv[2 * s + 1][1]);
      unsigned W = cvt_pk_bf16(pv[2 * s + 1][2], pv[2 * s + 1][3]);
      permlane32_swap(X, Z);   // X=w0, Z=w1
      permlane32_swap(Y, W);   // Y=w2, W=w3
      bf16x8 pa;
      unsigned* pw = (unsigned*)&pa;
      pw[0] = X; pw[1] = Z; pw[2] = Y; pw[3] = W;
#pragma unroll
      for (int c = 0; c < 4; ++c) {
        const unsigned* vp = &sVt2[c * 16 + l16][s * 16 + quad * 4];
        bf16x4 vlo = *(const bf16x4*)vp;
        bf16x4 vhi = *(const bf16x4*)(vp + 2);
        bf16x8 vf = {vlo[0], vlo[1], vlo[2], vlo[3], vhi[0], vhi[1], vhi[2], vhi[3]};
        oacc[c] = __builtin_amdgcn_mfma_f32_16x16x32_bf16(pa, vf, oacc[c], 0, 0, 0);
      }
    }

#pragma unroll
    for (int r = 0; r < 4; ++r) bias0[r] += c64;   // k0 advances 64 next tile
  };

  // prologue: issue first tile's loads (regs only; LDS writes in tile 0)
  loadK(kts2);
  loadV(kts2);
  // all tiles except the diagonal (last of the LAST chunk) are fully causal
  const int kfull = (kte == n) ? (kte - 1) : kte;
  for (int kt = kts2; kt < kfull; ++kt) tile(kt, BoolT<false>{});
  if (kte == n) tile(n - 1, BoolT<true>{});   // diagonal tile: mask

  // epilogue: unnormalized O partial (bf16) + l partial (fp32)
  {
    // total l for query l16: reduce over the 4 quad lanes
    float lt = lsum;
    lt += __shfl_xor(lt, 16);
    lt += __shfl_xor(lt, 32);
    const int pidx = (b * NH + h) * NCHB + item;
    short* po = Po + (size_t)pidx * 4096;   // [64 rows][64 dims]
    float* pl = Pl + (size_t)pidx * 64;
#pragma unroll
    for (int r = 0; r < 4; ++r) {
      const int row = wv * 16 + quad * 4 + r;
      const float lr = __shfl(lt, quad * 4 + r, 16);  // l of query quad*4+r
      if (l16 == 0) pl[row] = lr;
#pragma unroll
      for (int c = 0; c < 4; ++c)
        po[row * 64 + c * 16 + l16] = f2bf(oacc[c][r]);
    }
  }
}

// ---------------------------------------------------------------------------
// Combine: O[row] = (sum_j Oj)/(sum_j lj) -> bf16, for ALL query tiles.
// chunks per qt: (qt>>3)+1; slab base cum(qt) = (g+1)*(4g + (qt&7)), g=qt>>3.
// Chunks with j*8+8 <= qt-D(h) were fully skipped by flash (no slab written)
// -> start at jmin = (qt-D)>>3 (same D(h) formula as flash, bit-exact).
// ---------------------------------------------------------------------------
__global__ __launch_bounds__(256) void combine(const short* __restrict__ Po,
                                               const float* __restrict__ Pl,
                                               short* __restrict__ O) {
  const int g = blockIdx.x * 32 + (threadIdx.x >> 3);   // 0..65535
  const int d = (threadIdx.x & 7) << 3;
  const int row = g & 63;
  const int qt  = (g >> 6) & 31;
  const int h   = (g >> 11) & 15;
  const int b   = g >> 15;
  const int gq  = qt >> 3;
  const int nch = gq + 1;
  const int cum = (gq + 1) * (4 * gq + (qt & 7));
  const int sbase = (b * NH + h) * NCHB + cum;

  const int D = alibi_D(h);
  const int m = qt - D;
  const int jmin = (m > 0) ? (m >> 3) : 0;   // chunk j empty iff j*8+8 <= m

  float l = 0.f;
  float acc[8] = {0.f, 0.f, 0.f, 0.f, 0.f, 0.f, 0.f, 0.f};
  for (int jj = jmin; jj < nch; ++jj) {
    l += Pl[(size_t)(sbase + jj) * 64 + row];
    const short* p = Po + (size_t)(sbase + jj) * 4096 + row * 64 + d;
    bf16x8 a = *(const bf16x8*)p;
#pragma unroll
    for (int e = 0; e < 8; ++e) acc[e] += bf2f(a[e]);
  }
  const float inv = 1.0f / fmaxf(l, 1e-37f);
  const int qi = qt * 64 + row;
  short* orow = O + (size_t)b * T_SEQ * DM + (size_t)qi * DM + h * HD + d;
  bf16x8 o;
#pragma unroll
  for (int e = 0; e < 8; ++e) o[e] = f2bf(acc[e] * inv);
  *(bf16x8*)orow = o;
}

// ---------------------------------------------------------------------------
extern "C" void kernel_launch(void* const* d_in, const int* in_sizes, int n_in,
                              void* d_out, int out_size, void* d_ws, size_t ws_size,
                              hipStream_t stream) {
  float* out = (float*)d_out;   // fp32 output

  short* ws = (short*)d_ws;
  const size_t plane = (size_t)NROW * DM;   // 4M elements
  const size_t wsz   = (size_t)DM * DM;     // 1M elements
  const size_t nslab = (size_t)32 * NCHB;   // 2560 partial slabs
  short* xb  = ws;
  short* Wqb = xb + plane;
  short* Wkb = Wqb + wsz;
  short* Wvb = Wkb + wsz;
  short* Wob = Wvb + wsz;
  short* Qb  = Wob + wsz;
  short* Kb  = Qb + plane;
  short* Vb  = Kb + plane;
  short* Ab  = Vb + plane;
  short* Po  = Ab + plane;                  // 2560 slabs * 4096 bf16 = 21 MB
  float* Pl  = (float*)(Po + nslab * 4096); // 2560 * 64 fp32 = 655 KB

  dim3 blk(256);
  convert_all<<<8192, blk, 0, stream>>>(
      (const float*)d_in[0], (const float*)d_in[1], (const float*)d_in[2],
      (const float*)d_in[3], (const float*)d_in[4],
      xb, Wqb, Wkb, Wvb, Wob);

  gemm_qkv<<<dim3(NROW / 128, DM / 128, 3), blk, 0, stream>>>(xb, Wqb, Wkb, Wvb, Qb, Kb, Vb);
  flash_alibi<<<dim3(NCHB, NH, 2), blk, 0, stream>>>(Qb, Kb, Vb, Ab, Po, Pl);
  combine<<<2048, blk, 0, stream>>>(Po, Pl, Ab);
  gemm_out<<<dim3(NROW / 64, DM / 128, 1), blk, 0, stream>>>(Ab, Wob, out);
}